// Round 1
// baseline (14.772 us; speedup 1.0000x reference)
//
#include <hip/hip_runtime.h>

// CenterLoss collapses to: loss = (1/B) * sum_b clip(||e_b - c_{label_b}||^2, 1e-12, 1e12)
//                                 + (C-1)*1e-12   (zeros clamped up by clip's lower bound)
// B=4096, D=256, C=32000. Pure gather + rowwise reduce: ~8 MB traffic.

#define BATCH 4096
#define FEAT_DIM 256
#define NUM_CLASSES 32000

__global__ __launch_bounds__(256) void center_dist_kernel(
    const float* __restrict__ emb,      // [BATCH, FEAT_DIM]
    const int* __restrict__ labels,     // [BATCH]
    const float* __restrict__ centers,  // [NUM_CLASSES, FEAT_DIM]
    float* __restrict__ partial)        // [BATCH]
{
    // one 64-lane wave per row
    const int gtid = blockIdx.x * blockDim.x + threadIdx.x;
    const int row  = gtid >> 6;
    const int lane = threadIdx.x & 63;
    if (row >= BATCH) return;

    const int lbl = labels[row];

    const float4 e = *reinterpret_cast<const float4*>(emb + (size_t)row * FEAT_DIM + lane * 4);
    const float4 c = *reinterpret_cast<const float4*>(centers + (size_t)lbl * FEAT_DIM + lane * 4);

    const float d0 = e.x - c.x;
    const float d1 = e.y - c.y;
    const float d2 = e.z - c.z;
    const float d3 = e.w - c.w;
    float s = d0 * d0 + d1 * d1 + d2 * d2 + d3 * d3;

    // wave64 reduce
    #pragma unroll
    for (int off = 32; off > 0; off >>= 1)
        s += __shfl_down(s, off, 64);

    if (lane == 0) {
        s = fminf(fmaxf(s, 1e-12f), 1e12f);
        partial[row] = s;
    }
}

__global__ __launch_bounds__(256) void reduce_kernel(
    const float* __restrict__ partial,  // [BATCH]
    float* __restrict__ out)            // [1]
{
    __shared__ float sm[256];
    float s = 0.0f;
    for (int i = threadIdx.x; i < BATCH; i += 256)
        s += partial[i];
    sm[threadIdx.x] = s;
    __syncthreads();
    #pragma unroll
    for (int off = 128; off > 0; off >>= 1) {
        if (threadIdx.x < off) sm[threadIdx.x] += sm[threadIdx.x + off];
        __syncthreads();
    }
    if (threadIdx.x == 0) {
        // LAMBDA_C = 1.0; the (C-1) clamped zeros each contribute 1e-12.
        out[0] = sm[0] / (float)BATCH + (float)(NUM_CLASSES - 1) * 1e-12f;
    }
}

extern "C" void kernel_launch(void* const* d_in, const int* in_sizes, int n_in,
                              void* d_out, int out_size, void* d_ws, size_t ws_size,
                              hipStream_t stream) {
    const float* emb     = (const float*)d_in[0];
    const int*   labels  = (const int*)d_in[1];
    const float* centers = (const float*)d_in[2];
    float* out     = (float*)d_out;
    float* partial = (float*)d_ws;  // BATCH floats = 16 KB

    // 64 lanes per row, 4 rows per 256-thread block -> 1024 blocks
    const int threads = 256;
    const int blocks  = (BATCH * 64) / threads;
    center_dist_kernel<<<blocks, threads, 0, stream>>>(emb, labels, centers, partial);
    reduce_kernel<<<1, threads, 0, stream>>>(partial, out);
}

// Round 2
// 14.585 us; speedup vs baseline: 1.0128x; 1.0128x over previous
//
#include <hip/hip_runtime.h>

// CenterLoss collapses to: loss = (1/B) * sum_b clip(||e_b - c_{label_b}||^2, 1e-12, 1e12)
//                                 + (C-1)*1e-12   (zeros clamped up by clip's lower bound)
// B=4096, D=256, C=32000. Pure gather + rowwise reduce: ~8.4 MB traffic -> launch-bound.
//
// Single fused kernel: 256 blocks x 256 threads; each wave (4/block) owns 4 rows.
// Per row: 64 lanes load one float4 of emb + gathered center, squared-diff,
// butterfly shuffle-reduce, per-row clip. Block combines 4 wave sums in LDS and
// issues ONE atomicAdd of block_sum/B to d_out (zeroed by a memset node first).
// 256 same-address fp32 atomics: order nondeterminism ~1e-4 << 10.24 threshold.

#define BATCH 4096
#define FEAT_DIM 256
#define NUM_CLASSES 32000

__global__ __launch_bounds__(256) void center_loss_fused(
    const float* __restrict__ emb,      // [BATCH, FEAT_DIM]
    const int* __restrict__ labels,     // [BATCH]
    const float* __restrict__ centers,  // [NUM_CLASSES, FEAT_DIM]
    float* __restrict__ out)            // [1], pre-zeroed
{
    const int wave = threadIdx.x >> 6;
    const int lane = threadIdx.x & 63;
    const int rowBase = blockIdx.x * 16 + wave * 4;

    float acc = 0.0f;
    #pragma unroll
    for (int r = 0; r < 4; ++r) {
        const int row = rowBase + r;
        const int lbl = labels[row];  // wave-uniform -> scalar load
        const float4 e = *reinterpret_cast<const float4*>(emb + (size_t)row * FEAT_DIM + lane * 4);
        const float4 c = *reinterpret_cast<const float4*>(centers + (size_t)lbl * FEAT_DIM + lane * 4);
        const float d0 = e.x - c.x;
        const float d1 = e.y - c.y;
        const float d2 = e.z - c.z;
        const float d3 = e.w - c.w;
        float s = d0 * d0 + d1 * d1 + d2 * d2 + d3 * d3;
        // wave64 butterfly reduce (all lanes end with the row sum)
        #pragma unroll
        for (int off = 1; off < 64; off <<= 1)
            s += __shfl_xor(s, off, 64);
        acc += fminf(fmaxf(s, 1e-12f), 1e12f);  // per-row clip, then accumulate
    }

    __shared__ float wsum[4];
    if (lane == 0) wsum[wave] = acc;
    __syncthreads();
    if (threadIdx.x == 0) {
        float bs = (wsum[0] + wsum[1] + wsum[2] + wsum[3]) * (1.0f / (float)BATCH);
        if (blockIdx.x == 0)
            bs += (float)(NUM_CLASSES - 1) * 1e-12f;  // clamped zeros' contribution
        atomicAdd(out, bs);
    }
}

extern "C" void kernel_launch(void* const* d_in, const int* in_sizes, int n_in,
                              void* d_out, int out_size, void* d_ws, size_t ws_size,
                              hipStream_t stream) {
    const float* emb     = (const float*)d_in[0];
    const int*   labels  = (const int*)d_in[1];
    const float* centers = (const float*)d_in[2];
    float* out = (float*)d_out;

    hipMemsetAsync(out, 0, sizeof(float), stream);
    // 256 blocks x 16 rows = 4096 rows
    center_loss_fused<<<256, 256, 0, stream>>>(emb, labels, centers, out);
}